// Round 2
// baseline (731.792 us; speedup 1.0000x reference)
//
#include <hip/hip_runtime.h>

#define D_ 128
#define N_ 2048
#define BH_ 128

typedef __attribute__((ext_vector_type(8))) short short8;
typedef __attribute__((ext_vector_type(4))) float f32x4;

#define MFMA_BF16(a, b, c) __builtin_amdgcn_mfma_f32_16x16x32_bf16((a), (b), (c), 0, 0, 0)

static __device__ __forceinline__ unsigned short f2bf(float x) {
    unsigned int u = __builtin_bit_cast(unsigned int, x);
    u += 0x7fffu + ((u >> 16) & 1u);          // round-to-nearest-even
    return (unsigned short)(u >> 16);
}
static __device__ __forceinline__ float bf2f(unsigned short h) {
    unsigned int u = ((unsigned int)h) << 16;
    return __builtin_bit_cast(float, u);
}
static __device__ __forceinline__ void split8(const float* x, short8* hi, short8* lo) {
    short8 h, l;
#pragma unroll
    for (int i = 0; i < 8; ++i) {
        unsigned short hh = f2bf(x[i]);
        h[i] = (short)hh;
        l[i] = (short)f2bf(x[i] - bf2f(hh));
    }
    *hi = h; *lo = l;
}
static __device__ __forceinline__ short8 ones_frag() {
    short8 o;
#pragma unroll
    for (int i = 0; i < 8; ++i) o[i] = (short)0x3F80;  // bf16(1.0)
    return o;
}

// ---------------------------------------------------------------------------
// k0: split a^T into bf16 hi/lo, layout [h][j][i] (i contiguous) — the exact
// A-fragment layout k2's S1 needs. One block per (head, 32-row i-chunk).
// ---------------------------------------------------------------------------
__global__ __launch_bounds__(256) void k0_split_a(
    const float* __restrict__ Ag,
    unsigned short* __restrict__ aThi, unsigned short* __restrict__ aTlo)
{
    const int head  = blockIdx.x >> 2;
    const int chunk = blockIdx.x & 3;          // i-chunk of 32
    const float* ah = Ag + ((size_t)head << 14);
    __shared__ __align__(16) float la[32][132];
    {
        const int il = threadIdx.x >> 3;        // 0..31 (local i)
        const int c0 = (threadIdx.x & 7) * 16;  // j start
        const float* p = ah + (size_t)(chunk * 32 + il) * D_ + c0;
#pragma unroll
        for (int g = 0; g < 4; ++g)
            *(f32x4*)&la[il][c0 + g * 4] = *(const f32x4*)(p + g * 4);
    }
    __syncthreads();
    const int j  = threadIdx.x >> 1;
    const int ih = (threadIdx.x & 1) * 16;
    float x[16];
#pragma unroll
    for (int ii = 0; ii < 16; ++ii) x[ii] = la[ih + ii][j];
    short8 h0, l0, h1, l1;
    split8(&x[0], &h0, &l0);
    split8(&x[8], &h1, &l1);
    const size_t off = ((size_t)head << 14) + (size_t)j * D_ + chunk * 32 + ih;
    *(short8*)(aThi + off)     = h0;
    *(short8*)(aThi + off + 8) = h1;
    *(short8*)(aTlo + off)     = l0;
    *(short8*)(aTlo + off + 8) = l1;
}

// ---------------------------------------------------------------------------
// k1: per (head, m-split of 256 keys): E = exp(a@k), accumulate
// accT[vd][t] += (E@v)^T and lsum[t] += rowsum(bf16 E) via ones-MFMA.
// Register-prefetched staging: next chunk's global loads issued right after
// the consume barrier, hidden behind the MFMA section. XCD swizzle: all 8
// splits of a head share blockIdx % 8 -> same XCD L2 for the atomics.
// ---------------------------------------------------------------------------
__global__ __launch_bounds__(256, 2) void k1_agg(
    const float* __restrict__ Ag, const float* __restrict__ Kg,
    const float* __restrict__ Vg, float* __restrict__ accT,
    float* __restrict__ lsum)
{
    const int head  = blockIdx.x & 127;
    const int split = blockIdx.x >> 7;   // 0..7
    const float* ah = Ag + (size_t)head * (D_ * D_);
    const float* kh = Kg + (size_t)head * (D_ * N_);
    const float* vh = Vg + (size_t)head * (N_ * D_);
    float* accTh = accT + (size_t)head * (D_ * D_);
    float* lh    = lsum + head * D_;

    const int tid  = threadIdx.x;
    const int lane = tid & 63;
    const int w    = tid >> 6;   // wave owns agent rows [w*32, w*32+32)
    const int l15  = lane & 15;
    const int qd   = lane >> 4;

    __shared__ __align__(16) short kt_hi[32][136];  // k^T chunk [m][j]
    __shared__ __align__(16) short kt_lo[32][136];
    __shared__ __align__(16) short vt[128][40];     // v^T chunk [vd][m]
    __shared__ __align__(16) short eb[4][32][40];   // per-wave E [t][m]

    // Preload a-fragments (B operand of S2^T): B[k=j][n=t] = a[t][j].
    short8 aBh[2][4], aBl[2][4];
#pragma unroll
    for (int nt = 0; nt < 2; ++nt) {
        const int t = w * 32 + nt * 16 + l15;
#pragma unroll
        for (int kt = 0; kt < 4; ++kt) {
            float x[8];
            const float* p = ah + t * D_ + kt * 32 + qd * 8;
            *(f32x4*)&x[0] = *(const f32x4*)p;
            *(f32x4*)&x[4] = *(const f32x4*)(p + 4);
            split8(x, &aBh[nt][kt], &aBl[nt][kt]);
        }
    }

    f32x4 agg[2][8];
    f32x4 lac[2];
#pragma unroll
    for (int tt = 0; tt < 2; ++tt) {
        f32x4 z = {0.f, 0.f, 0.f, 0.f};
        lac[tt] = z;
#pragma unroll
        for (int nt = 0; nt < 8; ++nt) agg[tt][nt] = z;
    }
    const short8 ones = ones_frag();

    // staging geometry
    const int ml  = (tid & 15) * 2;   // K: m pair
    const int j0  = (tid >> 4) * 8;   // K: j start
    const int vp  = (tid & 63) * 2;   // V: vd pair
    const int ml2 = (tid >> 6) * 8;   // V: m start

    // prefetch chunk 0 into registers
    float2 kr[8], vr[8];
    {
        const int m0 = split * 256;
#pragma unroll
        for (int jj = 0; jj < 8; ++jj)
            kr[jj] = *(const float2*)(kh + (size_t)(j0 + jj) * N_ + m0 + ml);
#pragma unroll
        for (int mm = 0; mm < 8; ++mm)
            vr[mm] = *(const float2*)(vh + (size_t)(m0 + ml2 + mm) * D_ + vp);
    }

    for (int c = 0; c < 8; ++c) {
        if (c) __syncthreads();
        {   // write prefetched regs -> LDS (split/convert)
            float xa[8], xb[8];
#pragma unroll
            for (int jj = 0; jj < 8; ++jj) { xa[jj] = kr[jj].x; xb[jj] = kr[jj].y; }
            short8 h, l;
            split8(xa, &h, &l);
            *(short8*)&kt_hi[ml][j0] = h;
            *(short8*)&kt_lo[ml][j0] = l;
            split8(xb, &h, &l);
            *(short8*)&kt_hi[ml + 1][j0] = h;
            *(short8*)&kt_lo[ml + 1][j0] = l;
            short8 va, vb;
#pragma unroll
            for (int mm = 0; mm < 8; ++mm) {
                va[mm] = (short)f2bf(vr[mm].x);
                vb[mm] = (short)f2bf(vr[mm].y);
            }
            *(short8*)&vt[vp][ml2]     = va;
            *(short8*)&vt[vp + 1][ml2] = vb;
        }
        __syncthreads();
        if (c < 7) {   // issue next chunk's loads; latency hidden by MFMAs below
            const int m1 = split * 256 + (c + 1) * 32;
#pragma unroll
            for (int jj = 0; jj < 8; ++jj)
                kr[jj] = *(const float2*)(kh + (size_t)(j0 + jj) * N_ + m1 + ml);
#pragma unroll
            for (int mm = 0; mm < 8; ++mm)
                vr[mm] = *(const float2*)(vh + (size_t)(m1 + ml2 + mm) * D_ + vp);
        }

        // S2^T: D[m][t] = sum_j k[j][m] * a[t][j]  (3-term bf16 split)
        f32x4 s[2][2];
        {
            f32x4 z = {0.f, 0.f, 0.f, 0.f};
            s[0][0] = z; s[0][1] = z; s[1][0] = z; s[1][1] = z;
        }
#pragma unroll
        for (int kt = 0; kt < 4; ++kt) {
            short8 Ah[2], Al[2];
#pragma unroll
            for (int mt = 0; mt < 2; ++mt) {
                Ah[mt] = *(const short8*)&kt_hi[mt * 16 + l15][kt * 32 + qd * 8];
                Al[mt] = *(const short8*)&kt_lo[mt * 16 + l15][kt * 32 + qd * 8];
            }
#pragma unroll
            for (int mt = 0; mt < 2; ++mt)
#pragma unroll
            for (int nt = 0; nt < 2; ++nt) {
                s[mt][nt] = MFMA_BF16(Ah[mt], aBh[nt][kt], s[mt][nt]);
                s[mt][nt] = MFMA_BF16(Ah[mt], aBl[nt][kt], s[mt][nt]);
                s[mt][nt] = MFMA_BF16(Al[mt], aBh[nt][kt], s[mt][nt]);
            }
        }
        // exp (no max subtraction; range safe) -> bf16 -> b64 into eb[t][m]
#pragma unroll
        for (int mt = 0; mt < 2; ++mt)
#pragma unroll
        for (int nt = 0; nt < 2; ++nt) {
            const unsigned int e0 = f2bf(__expf(s[mt][nt][0]));
            const unsigned int e1 = f2bf(__expf(s[mt][nt][1]));
            const unsigned int e2 = f2bf(__expf(s[mt][nt][2]));
            const unsigned int e3 = f2bf(__expf(s[mt][nt][3]));
            const unsigned long long pk =
                (unsigned long long)(e0 | (e1 << 16)) |
                ((unsigned long long)(e2 | (e3 << 16)) << 32);
            *(unsigned long long*)&eb[w][nt * 16 + l15][mt * 16 + qd * 4] = pk;
        }
        // PV: agg[t][vd] += E[t][m] * v^T; ones-MFMA row sums (same-wave LDS)
        short8 Ef[2];
#pragma unroll
        for (int tt = 0; tt < 2; ++tt)
            Ef[tt] = *(const short8*)&eb[w][tt * 16 + l15][qd * 8];
#pragma unroll
        for (int nt = 0; nt < 8; ++nt) {
            const short8 Bv = *(const short8*)&vt[nt * 16 + l15][qd * 8];
            agg[0][nt] = MFMA_BF16(Ef[0], Bv, agg[0][nt]);
            agg[1][nt] = MFMA_BF16(Ef[1], Bv, agg[1][nt]);
        }
        lac[0] = MFMA_BF16(Ef[0], ones, lac[0]);
        lac[1] = MFMA_BF16(Ef[1], ones, lac[1]);
    }

    // epilogue: atomic accumulate partials
#pragma unroll
    for (int tt = 0; tt < 2; ++tt) {
        const int t = w * 32 + tt * 16 + qd * 4;
#pragma unroll
        for (int nt = 0; nt < 8; ++nt) {
            const int vd = nt * 16 + l15;
#pragma unroll
            for (int r = 0; r < 4; ++r)
                atomicAdd(&accTh[vd * D_ + t + r], agg[tt][nt][r]);
        }
        if (l15 == 0) {
#pragma unroll
            for (int r = 0; r < 4; ++r)
                atomicAdd(&lh[t + r], lac[tt][r]);
        }
    }
}

// ---------------------------------------------------------------------------
// k1b: agg_hat[h][vd][t] = bf16( accT[h][vd][t] / lsum[h][t] )
// ---------------------------------------------------------------------------
__global__ __launch_bounds__(256) void k1b_norm(
    const float* __restrict__ accT, const float* __restrict__ lsum,
    unsigned short* __restrict__ aggh)
{
    const int head = blockIdx.x >> 3;
    const int vd   = ((blockIdx.x & 7) << 4) + (threadIdx.x >> 4);
    const int t0   = (threadIdx.x & 15) * 8;
    const float* src = accT + ((size_t)head << 14) + (size_t)vd * D_ + t0;
    const float* ls  = lsum + head * D_ + t0;
    f32x4 a0 = *(const f32x4*)src;
    f32x4 a1 = *(const f32x4*)(src + 4);
    f32x4 l0 = *(const f32x4*)ls;
    f32x4 l1 = *(const f32x4*)(ls + 4);
    short8 o;
#pragma unroll
    for (int r = 0; r < 4; ++r) {
        o[r]     = (short)f2bf(a0[r] * __builtin_amdgcn_rcpf(l0[r]));
        o[4 + r] = (short)f2bf(a1[r] * __builtin_amdgcn_rcpf(l1[r]));
    }
    *(short8*)(aggh + ((size_t)head << 14) + (size_t)vd * D_ + t0) = o;
}

// ---------------------------------------------------------------------------
// k2: per (head, 64-query tile): s1^T[j][n] = sum_i aT[j][i] q[n][i]
// (3-term split; aT hi/lo fragments straight from global — L1/L2-hot,
// shared by all 4 waves), column softmax (2 shuffles), P -> LDS [n][t]
// (same-wave), PV with agg_hat fragments from global, l1 via ones-MFMA.
// 3 barriers total; q half 1 prefetched during half 0's MFMAs.
// ---------------------------------------------------------------------------
__global__ __launch_bounds__(256, 4) void k2_out(
    const float* __restrict__ Qg,
    const unsigned short* __restrict__ aThi,
    const unsigned short* __restrict__ aTlo,
    const unsigned short* __restrict__ aggh,
    float* __restrict__ outg)
{
    const int head = blockIdx.x & 127;    // same-head tiles share an XCD
    const int nb   = blockIdx.x >> 7;     // 0..31
    const int n0   = nb * 64;
    const float* qh = Qg + (size_t)head * (N_ * D_);
    const unsigned short* athi = aThi + ((size_t)head << 14);
    const unsigned short* atlo = aTlo + ((size_t)head << 14);
    const unsigned short* agh  = aggh + ((size_t)head << 14);
    float* oh = outg + (size_t)head * (N_ * D_);

    const int tid  = threadIdx.x;
    const int lane = tid & 63;
    const int w    = tid >> 6;   // wave owns n-rows [w*16, w*16+16)
    const int l15  = lane & 15;
    const int qd   = lane >> 4;

    __shared__ __align__(16) short qhi[64][72];
    __shared__ __align__(16) short qlo[64][72];
    __shared__ __align__(16) short Pbuf[64][136];

    const int sn = tid >> 2;          // staging row 0..63
    const int si = (tid & 3) * 16;    // staging i start

    f32x4 qreg[4];
#pragma unroll
    for (int g = 0; g < 4; ++g)
        qreg[g] = *(const f32x4*)(qh + (size_t)(n0 + sn) * D_ + si + g * 4);

    f32x4 sA[8];
    {
        f32x4 z = {0.f, 0.f, 0.f, 0.f};
#pragma unroll
        for (int mt = 0; mt < 8; ++mt) sA[mt] = z;
    }

#pragma unroll
    for (int half = 0; half < 2; ++half) {
        if (half) __syncthreads();           // readers of qhi/qlo done
        {
            float x[16];
#pragma unroll
            for (int g = 0; g < 4; ++g) *(f32x4*)&x[g * 4] = qreg[g];
            short8 h0, l0, h1, l1;
            split8(&x[0], &h0, &l0);
            split8(&x[8], &h1, &l1);
            *(short8*)&qhi[sn][si]     = h0;
            *(short8*)&qhi[sn][si + 8] = h1;
            *(short8*)&qlo[sn][si]     = l0;
            *(short8*)&qlo[sn][si + 8] = l1;
        }
        __syncthreads();
        if (half == 0) {   // prefetch q half 1 during MFMAs below
#pragma unroll
            for (int g = 0; g < 4; ++g)
                qreg[g] = *(const f32x4*)(qh + (size_t)(n0 + sn) * D_ + 64 + si + g * 4);
        }
#pragma unroll
        for (int kqh = 0; kqh < 2; ++kqh) {
            const int i_glob = half * 64 + kqh * 32 + qd * 8;
            const short8 Bh = *(const short8*)&qhi[w * 16 + l15][kqh * 32 + qd * 8];
            const short8 Bl = *(const short8*)&qlo[w * 16 + l15][kqh * 32 + qd * 8];
#pragma unroll
            for (int mt = 0; mt < 8; ++mt) {
                const size_t aoff = (size_t)(mt * 16 + l15) * D_ + i_glob;
                const short8 Ah = *(const short8*)(athi + aoff);
                const short8 Al = *(const short8*)(atlo + aoff);
                sA[mt] = MFMA_BF16(Ah, Bh, sA[mt]);
                sA[mt] = MFMA_BF16(Ah, Bl, sA[mt]);
                sA[mt] = MFMA_BF16(Al, Bh, sA[mt]);
            }
        }
    }

    // column softmax over t for this lane's n = w*16 + l15
    {
        float mx = -1e30f;
#pragma unroll
        for (int mt = 0; mt < 8; ++mt)
#pragma unroll
            for (int r = 0; r < 4; ++r) mx = fmaxf(mx, sA[mt][r]);
        mx = fmaxf(mx, __shfl_xor(mx, 16));
        mx = fmaxf(mx, __shfl_xor(mx, 32));
        const int n = w * 16 + l15;
#pragma unroll
        for (int mt = 0; mt < 8; ++mt) {
            const unsigned int e0 = f2bf(__expf(sA[mt][0] - mx));
            const unsigned int e1 = f2bf(__expf(sA[mt][1] - mx));
            const unsigned int e2 = f2bf(__expf(sA[mt][2] - mx));
            const unsigned int e3 = f2bf(__expf(sA[mt][3] - mx));
            const unsigned long long pk =
                (unsigned long long)(e0 | (e1 << 16)) |
                ((unsigned long long)(e2 | (e3 << 16)) << 32);
            *(unsigned long long*)&Pbuf[n][mt * 16 + qd * 4] = pk;
        }
    }

    // PV: out^T[vd][n] = sum_t agg_hat[vd][t] P^T[t][n]  (same-wave Pbuf)
    f32x4 oA[8];
    f32x4 l1A;
    {
        f32x4 z = {0.f, 0.f, 0.f, 0.f};
#pragma unroll
        for (int mt = 0; mt < 8; ++mt) oA[mt] = z;
        l1A = z;
    }
    const short8 ones = ones_frag();
#pragma unroll
    for (int tq = 0; tq < 4; ++tq) {
        const short8 Bp = *(const short8*)&Pbuf[w * 16 + l15][tq * 32 + qd * 8];
#pragma unroll
        for (int mt = 0; mt < 8; ++mt) {
            const short8 Af = *(const short8*)(agh + (size_t)(mt * 16 + l15) * D_ + tq * 32 + qd * 8);
            oA[mt] = MFMA_BF16(Af, Bp, oA[mt]);
        }
        l1A = MFMA_BF16(ones, Bp, l1A);
    }

    const float inv = 1.0f / l1A[0];
    const int n = n0 + w * 16 + l15;
#pragma unroll
    for (int mt = 0; mt < 8; ++mt) {
        f32x4 ov;
#pragma unroll
        for (int r = 0; r < 4; ++r) ov[r] = oA[mt][r] * inv;
        *(f32x4*)(oh + (size_t)n * D_ + mt * 16 + qd * 4) = ov;
    }
}

extern "C" void kernel_launch(void* const* d_in, const int* in_sizes, int n_in,
                              void* d_out, int out_size, void* d_ws, size_t ws_size,
                              hipStream_t stream)
{
    (void)in_sizes; (void)n_in; (void)out_size; (void)ws_size;
    const float* q = (const float*)d_in[0];
    const float* a = (const float*)d_in[1];
    const float* k = (const float*)d_in[2];
    const float* v = (const float*)d_in[3];
    float* out = (float*)d_out;

    float* accT = (float*)d_ws;                              // [BH][vd][t]
    float* lsum = accT + (size_t)BH_ * D_ * D_;              // [BH][t]
    unsigned short* aThi = (unsigned short*)(lsum + (size_t)BH_ * D_);
    unsigned short* aTlo = aThi + (size_t)BH_ * D_ * D_;
    unsigned short* aggh = aTlo + (size_t)BH_ * D_ * D_;
    const size_t zbytes = ((size_t)BH_ * D_ * D_ + (size_t)BH_ * D_) * sizeof(float);

    hipMemsetAsync(d_ws, 0, zbytes, stream);
    k0_split_a<<<dim3(BH_ * 4), dim3(256), 0, stream>>>(a, aThi, aTlo);
    k1_agg<<<dim3(BH_ * 8), dim3(256), 0, stream>>>(a, k, v, accT, lsum);
    k1b_norm<<<dim3(BH_ * 8), dim3(256), 0, stream>>>(accT, lsum, aggh);
    k2_out<<<dim3(BH_ * 32), dim3(256), 0, stream>>>(q, aThi, aTlo, aggh, out);
}